// Round 1
// baseline (520.189 us; speedup 1.0000x reference)
//
#include <hip/hip_runtime.h>
#include <hip/hip_bf16.h>

// upfirdn2d: up=(2,2), down=(1,1), pad=((2,1),(2,1)), 4x4 kernel, gain=4 (=up_x*up_y)
// x: (16,64,128,128) f32 -> out: (16,64,255,255) f32
// Each output pixel = weighted sum of a 2x2 input patch; weights depend on
// (oy&1, ox&1) parity and are drawn from the flipped 4x4 kernel:
//   even parity -> flipped-K indices {3 (near tap), 1 (far tap)}
//   odd  parity -> flipped-K indices {2, 0}
// input base: i0 = (o>>1) - 1 + (o&1); taps at i0, i0+1. Only i0 == -1 at o==0
// is out of range (contributes 0); i0+1 <= 127 always.

#define IN_H 128
#define IN_W 128
#define OUT_H 255
#define OUT_W 255
#define PLANES 1024  // 16*64

__global__ __launch_bounds__(256) void upfirdn2d_kernel(
    const float* __restrict__ x,
    const float* __restrict__ k,   // 4x4, row-major, un-flipped, normalized
    float* __restrict__ out)
{
    // sw[py][a][px][b] = gain * K[ry][rx], the weight applied to input
    // (iy0+a, ix0+b) for an output pixel with parities (py, px).
    __shared__ float sw[2][2][2][2];
    const int tid = threadIdx.x;
    if (tid < 16) {
        const int py = (tid >> 3) & 1;
        const int a  = (tid >> 2) & 1;
        const int px = (tid >> 1) & 1;
        const int b  = tid & 1;
        // flipped-kernel index per (parity, tap): even->{3,1}, odd->{2,0}
        const int ry = py ? (a ? 0 : 2) : (a ? 1 : 3);
        const int rx = px ? (b ? 0 : 2) : (b ? 1 : 3);
        sw[py][a][px][b] = 4.0f * k[ry * 4 + rx];
    }
    __syncthreads();

    const int ox = tid;
    if (ox >= OUT_W) return;
    const int oy    = blockIdx.y;
    const int plane = blockIdx.z;

    const int py = oy & 1;
    const int px = ox & 1;
    const int iy0 = (oy >> 1) - 1 + py;   // may be -1 only when oy==0
    const int ix0 = (ox >> 1) - 1 + px;   // may be -1 only when ox==0

    const float w00 = sw[py][0][px][0];
    const float w01 = sw[py][0][px][1];
    const float w10 = sw[py][1][px][0];
    const float w11 = sw[py][1][px][1];

    const float* __restrict__ xp = x + (size_t)plane * (IN_H * IN_W);

    float acc = 0.0f;
    if (iy0 >= 0) {
        const float* __restrict__ r0 = xp + iy0 * IN_W;
        if (ix0 >= 0) acc += w00 * r0[ix0];
        acc += w01 * r0[ix0 + 1];
    }
    {
        const float* __restrict__ r1 = xp + (iy0 + 1) * IN_W;
        if (ix0 >= 0) acc += w10 * r1[ix0];
        acc += w11 * r1[ix0 + 1];
    }

    out[(size_t)plane * (OUT_H * OUT_W) + (size_t)oy * OUT_W + ox] = acc;
}

extern "C" void kernel_launch(void* const* d_in, const int* in_sizes, int n_in,
                              void* d_out, int out_size, void* d_ws, size_t ws_size,
                              hipStream_t stream) {
    const float* x = (const float*)d_in[0];
    const float* k = (const float*)d_in[1];
    float* out = (float*)d_out;

    dim3 block(256, 1, 1);
    dim3 grid(1, OUT_H, PLANES);   // one block per (output row, plane)
    upfirdn2d_kernel<<<grid, block, 0, stream>>>(x, k, out);
}

// Round 2
// 356.909 us; speedup vs baseline: 1.4575x; 1.4575x over previous
//
#include <hip/hip_runtime.h>

// upfirdn2d: up=(2,2), down=(1,1), pad=((2,1),(2,1)), 4x4 kernel, gain=4
// x: (16,64,128,128) f32 -> out: (16,64,255,255) f32
//
// Output pixel (oy,ox): parity (py,px)=(oy&1,ox&1) picks 4 weights from the
// flipped kernel; input taps at rows iy0,iy0+1, cols ix0,ix0+1 where
// i0 = (o>>1)-1+(o&1). Only i0==-1 at o==0 is OOB (contributes 0).
//
// Strategy: block = 16 consecutive output rows of one plane (a flat dword
// range). Stage the 10 needed input rows in LDS (float4 global loads, rows are
// 512B-aligned), zero-pad LDS col 0 for the ix=-1 tap. Bulk-store the output
// range as aligned float4 (head/tail 0..3 scalars since 255-wide rows shift
// alignment per row).

#define IN_H 128
#define IN_W 128
#define OUT_H 255
#define OUT_W 255
#define ROWS_PER_TILE 16
#define NTILES 16              // ceil(255/16)
#define LDS_STRIDE 130         // col index c holds input col c-1; c=0 is the zero pad
#define MAX_IN_ROWS 10

__global__ __launch_bounds__(256) void upfirdn2d_kernel(
    const float* __restrict__ x,
    const float* __restrict__ k,
    float* __restrict__ out)
{
    __shared__ float lw[16];                       // lw[((py<<1)|px)*4 + (a<<1)|b]
    __shared__ float li[MAX_IN_ROWS * LDS_STRIDE];

    const int tid   = threadIdx.x;
    const int tile  = blockIdx.x;
    const int plane = blockIdx.y;

    const int oy0       = tile * ROWS_PER_TILE;
    const int nrows_out = min(ROWS_PER_TILE, OUT_H - oy0);
    const int iy_lo     = (oy0 >> 1) - 1;                    // 8*tile - 1
    const int iy_hi     = min(IN_H - 1, (oy0 >> 1) + 8);
    const int n_in_rows = iy_hi - iy_lo + 1;

    // --- weight table: w[py][px][a][b] = gain * Kflip[sel] ---
    if (tid < 16) {
        const int py = (tid >> 3) & 1;
        const int px = (tid >> 2) & 1;
        const int a  = (tid >> 1) & 1;
        const int b  = tid & 1;
        const int ry = py ? (a ? 0 : 2) : (a ? 1 : 3);
        const int rx = px ? (b ? 0 : 2) : (b ? 1 : 3);
        lw[(((py << 1) | px) << 2) + ((a << 1) | b)] = 4.0f * k[ry * 4 + rx];
    }

    // --- stage input rows iy_lo..iy_hi into LDS (col offset +1; col0 = 0) ---
    {
        const float4* xp4 = (const float4*)(x + (size_t)plane * (IN_H * IN_W));
        const int nslots = n_in_rows * (IN_W / 4);           // float4 slots
        for (int s = tid; s < nslots; s += 256) {
            const int row = s >> 5;                          // / (128/4)
            const int c4  = s & 31;
            const int iy  = iy_lo + row;
            float4 v = make_float4(0.f, 0.f, 0.f, 0.f);
            if (iy >= 0) v = xp4[iy * (IN_W / 4) + c4];
            float* dst = &li[row * LDS_STRIDE + 1 + (c4 << 2)];
            dst[0] = v.x; dst[1] = v.y; dst[2] = v.z; dst[3] = v.w;
        }
        if (tid < MAX_IN_ROWS) li[tid * LDS_STRIDE] = 0.0f;  // ix=-1 pad
    }
    __syncthreads();

    // one output element from LDS
    auto compute = [&](int oy, int ox) -> float {
        const int py = oy & 1, px = ox & 1;
        const int r  = ((oy >> 1) - 1 + py) - iy_lo;         // LDS row of top tap
        const int c  = (ox >> 1) + px;                       // = ix0 + 1
        const float4 w = *(const float4*)&lw[(((py << 1) | px) << 2)];
        const float* p0 = &li[r * LDS_STRIDE + c];
        const float* p1 = p0 + LDS_STRIDE;
        return w.x * p0[0] + w.y * p0[1] + w.z * p1[0] + w.w * p1[1];
    };

    const int out_base = plane * (OUT_H * OUT_W) + oy0 * OUT_W;
    const int n_out    = nrows_out * OUT_W;
    const int end_i    = out_base + n_out;
    const int astart   = (out_base + 3) & ~3;
    const int aend     = end_i & ~3;
    const int head_n   = astart - out_base;                  // 0..3
    const int tail_n   = end_i - aend;                       // 0..3

    if (tid < head_n) {                                      // rel = tid < 3 -> row 0
        out[out_base + tid] = compute(oy0, tid);
    }
    if (tid < tail_n) {
        const unsigned rel = (unsigned)(aend + tid - out_base);
        const unsigned q   = rel / 255u;
        out[aend + tid] = compute(oy0 + (int)q, (int)(rel - q * 255u));
    }

    const int ngroups = (aend - astart) >> 2;
    for (int g = tid; g < ngroups; g += 256) {
        const int f0 = astart + (g << 2);
        const unsigned rel = (unsigned)(f0 - out_base);
        const unsigned q   = rel / 255u;
        int ox = (int)(rel - q * 255u);
        int oy = oy0 + (int)q;
        float4 res;
        float* rp = &res.x;
#pragma unroll
        for (int j = 0; j < 4; ++j) {
            rp[j] = compute(oy, ox);
            if (++ox == OUT_W) { ox = 0; ++oy; }
        }
        *(float4*)(out + f0) = res;
    }
}

extern "C" void kernel_launch(void* const* d_in, const int* in_sizes, int n_in,
                              void* d_out, int out_size, void* d_ws, size_t ws_size,
                              hipStream_t stream) {
    const float* x = (const float*)d_in[0];
    const float* k = (const float*)d_in[1];
    float* out = (float*)d_out;

    dim3 block(256, 1, 1);
    dim3 grid(NTILES, 1024, 1);    // tiles-per-plane x planes (16*64)
    upfirdn2d_kernel<<<grid, block, 0, stream>>>(x, k, out);
}